// Round 4
// baseline (670.243 us; speedup 1.0000x reference)
//
#include <hip/hip_runtime.h>
#include <math.h>

#define S_DIM 1024
#define B_DIM 16
#define K_DIM 1024
#define QD_DIM 1024
#define KD_DIM 1024
#define MASK_NEG (-3.0e38f)

typedef unsigned short u16;
typedef unsigned int u32;
using short4v = __attribute__((ext_vector_type(4))) short;
using short8v = __attribute__((ext_vector_type(8))) short;
using float4v = __attribute__((ext_vector_type(4))) float;

#define MFMA(a, b, c) __builtin_amdgcn_mfma_f32_16x16x32_bf16(a, b, c, 0, 0, 0)

// async global->LDS, 16 B per lane; LDS dest = wave-uniform base + lane*16
__device__ __forceinline__ void load_lds16(const void* g, void* l) {
    __builtin_amdgcn_global_load_lds((const __attribute__((address_space(1))) u32*)g,
                                     (__attribute__((address_space(3))) u32*)l, 16, 0, 0);
}

// Split float4 -> packed hi bf16 (trunc) + packed lo bf16 of residual.
__device__ inline void split4(const float4 v, uint2& hi, uint2& lo) {
    u32 ax = __float_as_uint(v.x), ay = __float_as_uint(v.y);
    u32 az = __float_as_uint(v.z), aw = __float_as_uint(v.w);
    hi.x = __builtin_amdgcn_perm(ay, ax, 0x07060302u);
    hi.y = __builtin_amdgcn_perm(aw, az, 0x07060302u);
    float rx = v.x - __uint_as_float(ax & 0xFFFF0000u);
    float ry = v.y - __uint_as_float(ay & 0xFFFF0000u);
    float rz = v.z - __uint_as_float(az & 0xFFFF0000u);
    float rw = v.w - __uint_as_float(aw & 0xFFFF0000u);
    lo.x = __builtin_amdgcn_perm(__float_as_uint(ry), __float_as_uint(rx), 0x07060302u);
    lo.y = __builtin_amdgcn_perm(__float_as_uint(rw), __float_as_uint(rz), 0x07060302u);
}

__device__ __forceinline__ u16 hi16(float f) { return (u16)(__float_as_uint(f) >> 16); }
__device__ __forceinline__ u16 lo16(float f) {
    float r = f - __uint_as_float(__float_as_uint(f) & 0xFFFF0000u);
    return (u16)(__float_as_uint(r) >> 16);
}

// two b64 reads for padded (36-short row) buffers
__device__ inline short8v frag_load(const short* base) {
    short4v a = *(const short4v*)base;
    short4v b = *(const short4v*)(base + 4);
    return __builtin_shufflevector(a, b, 0, 1, 2, 3, 4, 5, 6, 7);
}

// ---------------------------------------------------------------------------
// Elementwise split: fp32 -> bf16 hi/lo arrays (same layout)
// ---------------------------------------------------------------------------
__global__ __launch_bounds__(256) void k_split(const float* __restrict__ in,
                                               u16* __restrict__ H, u16* __restrict__ L) {
    const size_t i = (size_t)blockIdx.x * 256 + threadIdx.x;
    float4 v = ((const float4*)in)[i];
    uint2 h, l;
    split4(v, h, l);
    ((uint2*)H)[i] = h;
    ((uint2*)L)[i] = l;
}

// ---------------------------------------------------------------------------
// Transpose+split: keys[b][k][d] fp32 -> keysT{H,L}[b][d][k] bf16
// ---------------------------------------------------------------------------
__global__ __launch_bounds__(256) void k_tsplit(const float* __restrict__ keys,
                                                u16* __restrict__ TH, u16* __restrict__ TL) {
    __shared__ float tile[64][65];
    const int b = blockIdx.z, k0 = blockIdx.x * 64, d0 = blockIdx.y * 64;
    const float* Kb = keys + (size_t)b * K_DIM * KD_DIM;
    const int t = threadIdx.x;
    const int rk = t >> 4;
    const int cd = (t & 15) * 4;
    #pragma unroll
    for (int i = 0; i < 4; ++i) {
        float4 v = *(const float4*)(Kb + (size_t)(k0 + rk + i * 16) * KD_DIM + d0 + cd);
        tile[cd + 0][rk + i * 16] = v.x;
        tile[cd + 1][rk + i * 16] = v.y;
        tile[cd + 2][rk + i * 16] = v.z;
        tile[cd + 3][rk + i * 16] = v.w;
    }
    __syncthreads();
    const int rd = t >> 4;
    const int ck = (t & 15) * 4;
    #pragma unroll
    for (int i = 0; i < 4; ++i) {
        const int d = rd + i * 16;
        float4 g;
        g.x = tile[d][ck + 0]; g.y = tile[d][ck + 1];
        g.z = tile[d][ck + 2]; g.w = tile[d][ck + 3];
        uint2 h, l;
        split4(g, h, l);
        const size_t off = (size_t)b * KD_DIM * K_DIM + (size_t)(d0 + d) * K_DIM + k0 + ck;
        *(uint2*)(TH + off) = h;
        *(uint2*)(TL + off) = l;
    }
}

// ---------------------------------------------------------------------------
// GEMM1: TQ[m][n] = sum_k Q[m][k]*W[n][k]; A=Qh/Ql DMA, B=W manual split.
// Output written as bf16 hi/lo (TQh, TQl) via LDS repack.
// ---------------------------------------------------------------------------
__global__ __launch_bounds__(256) void g1_mfma(const u16* __restrict__ Qh,
                                               const u16* __restrict__ Ql,
                                               const float* __restrict__ W,
                                               u16* __restrict__ TQh,
                                               u16* __restrict__ TQl) {
    __shared__ short LDS[17408];               // Ah[4096] Al[4096] Bh[4608] Bl[4608]
    short* Ah = LDS;
    short* Al = LDS + 4096;
    short* Bh = LDS + 8192;
    short* Bl = LDS + 12800;
    const int t = threadIdx.x, w = t >> 6, l = t & 63;
    const int wm = w >> 1, wn = w & 1, quad = l >> 4, l15 = l & 15;
    const int m0 = blockIdx.y * 128, n0 = blockIdx.x * 128;
    const int arow = w * 16 + (l >> 2);        // DMA row within round
    const int achk = (l & 3) * 8;              // shorts
    const int brr = t >> 3;                    // 0..31 manual B row base
    const int bcc = (t & 7) * 4;

    float4v acc[4][4] = {};

    for (int k0 = 0; k0 < QD_DIM; k0 += 32) {
        #pragma unroll
        for (int r = 0; r < 2; ++r) {
            const size_t goff = (size_t)(m0 + r * 64 + arow) * QD_DIM + k0 + achk;
            load_lds16(Qh + goff, Ah + (r * 64 + w * 16) * 32);
            load_lds16(Ql + goff, Al + (r * 64 + w * 16) * 32);
        }
        #pragma unroll
        for (int i = 0; i < 4; ++i) {
            const int r = brr + i * 32;
            float4 v = *(const float4*)(W + (size_t)(n0 + r) * QD_DIM + k0 + bcc);
            uint2 h, lo;
            split4(v, h, lo);
            *(uint2*)&Bh[r * 36 + bcc] = h;
            *(uint2*)&Bl[r * 36 + bcc] = lo;
        }
        __syncthreads();
        short8v ah[4], al[4];
        #pragma unroll
        for (int mt = 0; mt < 4; ++mt) {
            const int ar = (wm * 64 + mt * 16 + l15) * 32 + quad * 8;
            ah[mt] = *(const short8v*)&Ah[ar];
            al[mt] = *(const short8v*)&Al[ar];
        }
        #pragma unroll
        for (int nt = 0; nt < 4; ++nt) {
            const int br2 = (wn * 64 + nt * 16 + l15) * 36 + quad * 8;
            short8v bh = frag_load(&Bh[br2]);
            short8v bl = frag_load(&Bl[br2]);
            #pragma unroll
            for (int mt = 0; mt < 4; ++mt) acc[mt][nt] = MFMA(ah[mt], bh, acc[mt][nt]);
            #pragma unroll
            for (int mt = 0; mt < 4; ++mt) acc[mt][nt] = MFMA(al[mt], bh, acc[mt][nt]);
            #pragma unroll
            for (int mt = 0; mt < 4; ++mt) acc[mt][nt] = MFMA(ah[mt], bl, acc[mt][nt]);
        }
        __syncthreads();
    }
    // epilogue: hi then lo through LDS, wide stores
    short* C16 = LDS;  // [128][128]
    const int erow = t >> 1, ecol = (t & 1) * 64;
    #pragma unroll
    for (int mt = 0; mt < 4; ++mt)
        #pragma unroll
        for (int reg = 0; reg < 4; ++reg) {
            const int ml = wm * 64 + mt * 16 + quad * 4 + reg;
            #pragma unroll
            for (int nt = 0; nt < 4; ++nt)
                C16[ml * 128 + wn * 64 + nt * 16 + l15] = (short)hi16(acc[mt][nt][reg]);
        }
    __syncthreads();
    #pragma unroll
    for (int i = 0; i < 8; ++i) {
        const int jj = ((i + (t & 7)) & 7) * 8;
        *(short8v*)(TQh + (size_t)(m0 + erow) * KD_DIM + n0 + ecol + jj) =
            *(const short8v*)&C16[erow * 128 + ecol + jj];
    }
    __syncthreads();
    #pragma unroll
    for (int mt = 0; mt < 4; ++mt)
        #pragma unroll
        for (int reg = 0; reg < 4; ++reg) {
            const int ml = wm * 64 + mt * 16 + quad * 4 + reg;
            #pragma unroll
            for (int nt = 0; nt < 4; ++nt)
                C16[ml * 128 + wn * 64 + nt * 16 + l15] = (short)lo16(acc[mt][nt][reg]);
        }
    __syncthreads();
    #pragma unroll
    for (int i = 0; i < 8; ++i) {
        const int jj = ((i + (t & 7)) & 7) * 8;
        *(short8v*)(TQl + (size_t)(m0 + erow) * KD_DIM + n0 + ecol + jj) =
            *(const short8v*)&C16[erow * 128 + ecol + jj];
    }
}

// ---------------------------------------------------------------------------
// GEMM2 (per b): alpha[s][b][k] = sum_d TQ[s*16+b][d]*keys[b][k][d]; both DMA.
// ---------------------------------------------------------------------------
__global__ __launch_bounds__(256) void g2_mfma(const u16* __restrict__ TQh,
                                               const u16* __restrict__ TQl,
                                               const u16* __restrict__ KH,
                                               const u16* __restrict__ KL,
                                               const int* __restrict__ mask,
                                               float* __restrict__ alpha) {
    __shared__ short LDS[16384];               // Ah Al Bh Bl, each [128][32]
    short* Ah = LDS;
    short* Al = LDS + 4096;
    short* Bh = LDS + 8192;
    short* Bl = LDS + 12288;
    const int t = threadIdx.x, w = t >> 6, l = t & 63;
    const int wm = w >> 1, wn = w & 1, quad = l >> 4, l15 = l & 15;
    const int m0 = blockIdx.y * 128, n0 = blockIdx.x * 128;
    const int b = blockIdx.z;
    const int arow = w * 16 + (l >> 2);
    const int achk = (l & 3) * 8;

    const u16* KHb = KH + (size_t)b * K_DIM * KD_DIM;
    const u16* KLb = KL + (size_t)b * K_DIM * KD_DIM;

    float4v acc[4][4] = {};

    for (int k0 = 0; k0 < KD_DIM; k0 += 32) {
        #pragma unroll
        for (int r = 0; r < 2; ++r) {
            const size_t aoff = ((size_t)(m0 + r * 64 + arow) * B_DIM + b) * QD_DIM + k0 + achk;
            load_lds16(TQh + aoff, Ah + (r * 64 + w * 16) * 32);
            load_lds16(TQl + aoff, Al + (r * 64 + w * 16) * 32);
            const size_t boff = (size_t)(n0 + r * 64 + arow) * KD_DIM + k0 + achk;
            load_lds16(KHb + boff, Bh + (r * 64 + w * 16) * 32);
            load_lds16(KLb + boff, Bl + (r * 64 + w * 16) * 32);
        }
        __syncthreads();
        short8v ah[4], al[4];
        #pragma unroll
        for (int mt = 0; mt < 4; ++mt) {
            const int ar = (wm * 64 + mt * 16 + l15) * 32 + quad * 8;
            ah[mt] = *(const short8v*)&Ah[ar];
            al[mt] = *(const short8v*)&Al[ar];
        }
        #pragma unroll
        for (int nt = 0; nt < 4; ++nt) {
            const int br2 = (wn * 64 + nt * 16 + l15) * 32 + quad * 8;
            short8v bh = *(const short8v*)&Bh[br2];
            short8v bl = *(const short8v*)&Bl[br2];
            #pragma unroll
            for (int mt = 0; mt < 4; ++mt) acc[mt][nt] = MFMA(ah[mt], bh, acc[mt][nt]);
            #pragma unroll
            for (int mt = 0; mt < 4; ++mt) acc[mt][nt] = MFMA(al[mt], bh, acc[mt][nt]);
            #pragma unroll
            for (int mt = 0; mt < 4; ++mt) acc[mt][nt] = MFMA(ah[mt], bl, acc[mt][nt]);
        }
        __syncthreads();
    }
    int mk[4];
    #pragma unroll
    for (int nt = 0; nt < 4; ++nt)
        mk[nt] = mask[b * K_DIM + n0 + wn * 64 + nt * 16 + l15];
    #pragma unroll
    for (int mt = 0; mt < 4; ++mt)
        #pragma unroll
        for (int reg = 0; reg < 4; ++reg) {
            const int s = m0 + wm * 64 + mt * 16 + quad * 4 + reg;
            #pragma unroll
            for (int nt = 0; nt < 4; ++nt) {
                const int n = n0 + wn * 64 + nt * 16 + l15;
                alpha[((size_t)s * B_DIM + b) * K_DIM + n] = mk[nt] ? MASK_NEG : acc[mt][nt][reg];
            }
        }
}

// ---------------------------------------------------------------------------
// Softmax stats per row r = s*B+b
// ---------------------------------------------------------------------------
__global__ __launch_bounds__(256) void k_stats(const float* __restrict__ alpha,
                                               float* __restrict__ mx,
                                               float* __restrict__ il) {
    const int r = blockIdx.x;
    const int t = threadIdx.x;
    const float4 v = ((const float4*)(alpha + (size_t)r * K_DIM))[t];
    float m = fmaxf(fmaxf(v.x, v.y), fmaxf(v.z, v.w));
    #pragma unroll
    for (int o = 1; o < 64; o <<= 1) m = fmaxf(m, __shfl_xor(m, o, 64));
    __shared__ float redm[4];
    __shared__ float reds[4];
    const int wid = t >> 6;
    if ((t & 63) == 0) redm[wid] = m;
    __syncthreads();
    const float M = fmaxf(fmaxf(redm[0], redm[1]), fmaxf(redm[2], redm[3]));
    float s = expf(v.x - M) + expf(v.y - M) + expf(v.z - M) + expf(v.w - M);
    #pragma unroll
    for (int o = 1; o < 64; o <<= 1) s += __shfl_xor(s, o, 64);
    if ((t & 63) == 0) reds[wid] = s;
    __syncthreads();
    if (t == 0) {
        mx[r] = M;
        il[r] = 1.0f / (reds[0] + reds[1] + reds[2] + reds[3]);
    }
}

// ---------------------------------------------------------------------------
// GEMM3 (per b): out[s][b][d] = sum_k P[s][k]*keysT[b][d][k];
//   A = P manual (exp + split, padded rows), B = keysT DMA.
// ---------------------------------------------------------------------------
__global__ __launch_bounds__(256) void g3_mfma(const float* __restrict__ alpha,
                                               const u16* __restrict__ TH,
                                               const u16* __restrict__ TL,
                                               const float* __restrict__ mx,
                                               const float* __restrict__ il,
                                               float* __restrict__ outk) {
    __shared__ short LDS[17408];               // Ah[4608] Al[4608] Bh[4096] Bl[4096]
    __shared__ float Ms[128], Ls[128];
    short* Ah = LDS;
    short* Al = LDS + 4608;
    short* Bh = LDS + 9216;
    short* Bl = LDS + 13312;
    const int t = threadIdx.x, w = t >> 6, l = t & 63;
    const int wm = w >> 1, wn = w & 1, quad = l >> 4, l15 = l & 15;
    const int m0 = blockIdx.y * 128, n0 = blockIdx.x * 128;
    const int b = blockIdx.z;
    const int arow = w * 16 + (l >> 2);
    const int achk = (l & 3) * 8;
    const int prr = t >> 3;                    // manual P row base
    const int pcc = (t & 7) * 4;

    const u16* THb = TH + (size_t)b * KD_DIM * K_DIM;
    const u16* TLb = TL + (size_t)b * KD_DIM * K_DIM;

    if (t < 128) {
        Ms[t] = mx[(size_t)(m0 + t) * B_DIM + b];
        Ls[t] = il[(size_t)(m0 + t) * B_DIM + b];
    }
    __syncthreads();

    float4v acc[4][4] = {};

    for (int k0 = 0; k0 < K_DIM; k0 += 32) {
        #pragma unroll
        for (int r = 0; r < 2; ++r) {
            const size_t boff = (size_t)(n0 + r * 64 + arow) * K_DIM + k0 + achk;
            load_lds16(THb + boff, Bh + (r * 64 + w * 16) * 32);
            load_lds16(TLb + boff, Bl + (r * 64 + w * 16) * 32);
        }
        #pragma unroll
        for (int i = 0; i < 4; ++i) {
            const int r = prr + i * 32;
            float4 va = *(const float4*)(alpha + ((size_t)(m0 + r) * B_DIM + b) * K_DIM + k0 + pcc);
            const float Mv = Ms[r], Lv = Ls[r];
            float4 p;
            p.x = __expf(va.x - Mv) * Lv;
            p.y = __expf(va.y - Mv) * Lv;
            p.z = __expf(va.z - Mv) * Lv;
            p.w = __expf(va.w - Mv) * Lv;
            uint2 h, lo;
            split4(p, h, lo);
            *(uint2*)&Ah[r * 36 + pcc] = h;
            *(uint2*)&Al[r * 36 + pcc] = lo;
        }
        __syncthreads();
        short8v ah[4], al[4];
        #pragma unroll
        for (int mt = 0; mt < 4; ++mt) {
            const int ar = (wm * 64 + mt * 16 + l15) * 36 + quad * 8;
            ah[mt] = frag_load(&Ah[ar]);
            al[mt] = frag_load(&Al[ar]);
        }
        #pragma unroll
        for (int nt = 0; nt < 4; ++nt) {
            const int br2 = (wn * 64 + nt * 16 + l15) * 32 + quad * 8;
            short8v bh = *(const short8v*)&Bh[br2];
            short8v bl = *(const short8v*)&Bl[br2];
            #pragma unroll
            for (int mt = 0; mt < 4; ++mt) acc[mt][nt] = MFMA(ah[mt], bh, acc[mt][nt]);
            #pragma unroll
            for (int mt = 0; mt < 4; ++mt) acc[mt][nt] = MFMA(al[mt], bh, acc[mt][nt]);
            #pragma unroll
            for (int mt = 0; mt < 4; ++mt) acc[mt][nt] = MFMA(ah[mt], bl, acc[mt][nt]);
        }
        __syncthreads();
    }
    #pragma unroll
    for (int mt = 0; mt < 4; ++mt)
        #pragma unroll
        for (int reg = 0; reg < 4; ++reg) {
            const int s = m0 + wm * 64 + mt * 16 + quad * 4 + reg;
            #pragma unroll
            for (int nt = 0; nt < 4; ++nt) {
                const int n = n0 + wn * 64 + nt * 16 + l15;
                outk[((size_t)s * B_DIM + b) * KD_DIM + n] = acc[mt][nt][reg];
            }
        }
}

extern "C" void kernel_launch(void* const* d_in, const int* in_sizes, int n_in,
                              void* d_out, int out_size, void* d_ws, size_t ws_size,
                              hipStream_t stream) {
    const float* queries = (const float*)d_in[0];   // (S, B, QD)
    const float* keys    = (const float*)d_in[1];   // (B, K, KD)
    const int*   mask    = (const int*)d_in[2];     // (B, K)
    const float* W_in    = (const float*)d_in[3];   // (KD, QD)

    const size_t NM = (size_t)S_DIM * B_DIM * QD_DIM;   // 16M elements

    float* out_att   = (float*)d_out;                   // (S, B, KD) 64 MB
    float* out_alpha = (float*)d_out + NM;              // (S, B, K)  64 MB

    // ws: keysH/L (64 MB), later overwritten by keysTH/L; stats at tail
    u16* keysH  = (u16*)d_ws;
    u16* keysL  = keysH + NM;
    u16* keysTH = keysH;                                // aliases (sequenced)
    u16* keysTL = keysL;
    float* mx = (float*)(keysL + NM);
    float* il = mx + S_DIM * B_DIM;

    // Qh/Ql temp in the alpha output region (dead before g2 writes alpha)
    u16* Qh = (u16*)out_alpha;
    u16* Ql = Qh + NM;
    // TQh/TQl temp in the attened output region (dead before g3 writes it)
    u16* TQh = (u16*)out_att;
    u16* TQl = TQh + NM;

    dim3 blk(256);

    // 1) pre-split Q and keys to bf16 hi/lo
    k_split<<<dim3(16384), blk, 0, stream>>>(queries, Qh, Ql);
    k_split<<<dim3(16384), blk, 0, stream>>>(keys, keysH, keysL);

    // 2) TQ = Q @ W^T  (bf16x3), output pre-split
    dim3 grid1(KD_DIM / 128, (S_DIM * B_DIM) / 128);
    g1_mfma<<<grid1, blk, 0, stream>>>(Qh, Ql, W_in, TQh, TQl);

    // 3) alpha = TQ @ keys^T + mask (overwrites Qh/Ql region)
    dim3 grid2(K_DIM / 128, S_DIM / 128, B_DIM);
    g2_mfma<<<grid2, blk, 0, stream>>>(TQh, TQl, keysH, keysL, mask, out_alpha);

    // 4) softmax stats
    k_stats<<<dim3(S_DIM * B_DIM), blk, 0, stream>>>(out_alpha, mx, il);

    // 5) keysT pre-split (overwrites keysH/L — dead after g2)
    k_tsplit<<<dim3(16, 16, 16), blk, 0, stream>>>(keys, keysTH, keysTL);

    // 6) attened = softmax(alpha) @ keys (overwrites TQ region)
    dim3 grid3(KD_DIM / 128, S_DIM / 128, B_DIM);
    g3_mfma<<<grid3, blk, 0, stream>>>(out_alpha, keysTH, keysTL, mx, il, out_att);
}